// Round 5
// baseline (808.436 us; speedup 1.0000x reference)
//
#include <hip/hip_runtime.h>
#include <cstdint>

#define BLOCK_SIZE 128
#define NPOS 63   // 9*7 spatial positions per batch

// One thread per (batch, position). R1-R4 lesson: holding h1[64] live across
// the 4096-FMA loop triggers a register-allocator pathology (VGPR stuck at
// 52-68, ~2.2x VALU instruction bloat, immune to launch_bounds / waves_per_eu
// / asm pins). Fix: round-trip h1 through LDS, chunk-major [kc][thread]
// float4 layout (consecutive-address ds_read_b128 = conflict-free, imm
// offsets = no address VALU), and process outputs in 4 tiles of 16
// accumulators. Max live set ~40 VGPRs. W2 stays wave-uniform => s_load.
__global__ __launch_bounds__(BLOCK_SIZE) void carnet_fused(
    const float* __restrict__ x,      // (B, 9, 7) flat
    const int*   __restrict__ adj,    // (B, 45)
    const float* __restrict__ ctx,    // (B, 45)
    const float* __restrict__ gcn_W,  // (7, 7)
    const float* __restrict__ gcn_b,  // (7)
    const float* __restrict__ ctx_W,  // (45, 63)
    const float* __restrict__ ctx_b,  // (63)
    const float* __restrict__ W1,     // (64, 2)
    const float* __restrict__ b1,     // (64)
    const float* __restrict__ W2,     // (64, 64)
    const float* __restrict__ b2,     // (64)
    const float* __restrict__ W3,     // (2, 64)
    const float* __restrict__ b3,     // (2)
    float* __restrict__ out,          // (B, 2, 9, 7) flat
    int total)
{
    // [k-chunk][thread] so lane-consecutive float4 reads are bank-minimal
    // and the chunk index is a compile-time ds imm offset (kc*2048 bytes).
    __shared__ float4 hbuf[16][BLOCK_SIZE];   // 32 KiB

    const int t = threadIdx.x;
    const int tid = blockIdx.x * BLOCK_SIZE + t;
    if (tid >= total) return;
    const int b = tid / NPOS;
    const int p = tid - b * NPOS;
    const int n = p / 7;
    const int f = p - n * 7;

    // ---------------- adjacency -> 45-bit mask ----------------
    const int* ab = adj + b * 45;
    uint64_t am = 0;
#pragma unroll
    for (int i = 0; i < 45; ++i)
        am |= (uint64_t)(ab[i] != 0) << i;

    // Row i of upper triangle starts at S(i) = 9i - i(i-1)/2 (diag first).
    // A has diag forced to 1; row sum = 1 + popcount(j>i bits).
    float d[9];
#pragma unroll
    for (int i = 0; i < 9; ++i) {
        const int s = 9 * i - (i * (i - 1)) / 2;
        const int w = 8 - i;
        const uint64_t bits = (am >> (s + 1)) & ((1ull << w) - 1ull);
        const int rs = 1 + __popcll(bits);
        d[i] = __frsqrt_rn((float)rs);
    }

    // ---------------- z[n][f] = d[n] * sum_m wm * y[m][f] + gcn_b[f] ----
    const float* xb = x + b * 63;
    const int sn = 9 * n - (n * (n - 1)) / 2;
    float zacc = 0.f;
#pragma unroll
    for (int m = 0; m < 9; ++m) {
        int sh = sn + m - n;
        sh = sh < 0 ? 0 : sh;                     // clamp to avoid UB shift
        const bool conn = (m == n) || ((m > n) && ((am >> sh) & 1ull));
        const float wm = conn ? d[m] : 0.f;
        float ym = 0.f;                           // y[m][f] = x[m,:] . gcn_W[:,f]
#pragma unroll
        for (int k = 0; k < 7; ++k)
            ym = fmaf(xb[m * 7 + k], gcn_W[k * 7 + f], ym);
        zacc = fmaf(wm, ym, zacc);
    }
    const float zv = fmaf(d[n], zacc, gcn_b[f]);

    // ---------------- c[p] = relu(ctx . ctx_W[:,p] + ctx_b[p]) ----------
    const float* cb = ctx + b * 45;
    float cacc = ctx_b[p];
#pragma unroll
    for (int q = 0; q < 45; ++q)
        cacc = fmaf(cb[q], ctx_W[q * 63 + p], cacc);
    const float cv = fmaxf(cacc, 0.f);

    // ---------------- layer 1: 2 -> 64, relu, chunk -> LDS ---------------
#pragma unroll
    for (int kc = 0; kc < 16; ++kc) {
        float4 h;
        h.x = fmaxf(fmaf(W1[8*kc+0], zv, fmaf(W1[8*kc+1], cv, b1[4*kc+0])), 0.f);
        h.y = fmaxf(fmaf(W1[8*kc+2], zv, fmaf(W1[8*kc+3], cv, b1[4*kc+1])), 0.f);
        h.z = fmaxf(fmaf(W1[8*kc+4], zv, fmaf(W1[8*kc+5], cv, b1[4*kc+2])), 0.f);
        h.w = fmaxf(fmaf(W1[8*kc+6], zv, fmaf(W1[8*kc+7], cv, b1[4*kc+3])), 0.f);
        hbuf[kc][t] = h;
    }
    // No barrier needed: each thread reads back only its own LDS column;
    // same-thread DS ordering is enforced by lgkmcnt.

    // ------- layer 2 (64x64) in 4 o-tiles of 16 acc, fused layer 3 -------
    float o0 = b3[0];
    float o1 = b3[1];
#pragma unroll 1
    for (int ot = 0; ot < 4; ++ot) {
        float acc[16];
#pragma unroll
        for (int r = 0; r < 16; ++r)
            acc[r] = b2[16 * ot + r];

#pragma unroll 1
        for (int kb = 0; kb < 4; ++kb) {          // 4 chunks (16 k) per step
            const float4 hv0 = hbuf[4 * kb + 0][t];
            const float4 hv1 = hbuf[4 * kb + 1][t];
            const float4 hv2 = hbuf[4 * kb + 2][t];
            const float4 hv3 = hbuf[4 * kb + 3][t];
#pragma unroll
            for (int r = 0; r < 16; ++r) {
                const float* __restrict__ wr = W2 + (16 * ot + r) * 64 + 16 * kb;
                float a = acc[r];
                a = fmaf(wr[0],  hv0.x, a);
                a = fmaf(wr[1],  hv0.y, a);
                a = fmaf(wr[2],  hv0.z, a);
                a = fmaf(wr[3],  hv0.w, a);
                a = fmaf(wr[4],  hv1.x, a);
                a = fmaf(wr[5],  hv1.y, a);
                a = fmaf(wr[6],  hv1.z, a);
                a = fmaf(wr[7],  hv1.w, a);
                a = fmaf(wr[8],  hv2.x, a);
                a = fmaf(wr[9],  hv2.y, a);
                a = fmaf(wr[10], hv2.z, a);
                a = fmaf(wr[11], hv2.w, a);
                a = fmaf(wr[12], hv3.x, a);
                a = fmaf(wr[13], hv3.y, a);
                a = fmaf(wr[14], hv3.z, a);
                a = fmaf(wr[15], hv3.w, a);
                acc[r] = a;
            }
        }

#pragma unroll
        for (int r = 0; r < 16; ++r) {
            const float h2 = fmaxf(acc[r], 0.f);   // h2[o], never stored
            o0 = fmaf(W3[16 * ot + r],      h2, o0);
            o1 = fmaf(W3[64 + 16 * ot + r], h2, o1);
        }
    }

    float* ob = out + b * 126 + p;
    ob[0]  = o0;   // channel 0
    ob[63] = o1;   // channel 1
}

extern "C" void kernel_launch(void* const* d_in, const int* in_sizes, int n_in,
                              void* d_out, int out_size, void* d_ws, size_t ws_size,
                              hipStream_t stream) {
    const float* x     = (const float*)d_in[0];
    const int*   adj   = (const int*)  d_in[1];
    const float* ctx   = (const float*)d_in[2];
    const float* gcn_W = (const float*)d_in[3];
    const float* gcn_b = (const float*)d_in[4];
    const float* ctx_W = (const float*)d_in[5];
    const float* ctx_b = (const float*)d_in[6];
    const float* W1    = (const float*)d_in[7];
    const float* b1    = (const float*)d_in[8];
    const float* W2    = (const float*)d_in[9];
    const float* b2    = (const float*)d_in[10];
    const float* W3    = (const float*)d_in[11];
    const float* b3    = (const float*)d_in[12];
    float* out = (float*)d_out;

    const int total = in_sizes[0];  // B * 63 positions
    const int grid = (total + BLOCK_SIZE - 1) / BLOCK_SIZE;
    carnet_fused<<<grid, BLOCK_SIZE, 0, stream>>>(
        x, adj, ctx, gcn_W, gcn_b, ctx_W, ctx_b,
        W1, b1, W2, b2, W3, b3, out, total);
}

// Round 6
// 276.075 us; speedup vs baseline: 2.9283x; 2.9283x over previous
//
#include <hip/hip_runtime.h>
#include <cstdint>

#define BLOCK_SIZE 128
#define NPOS 63   // 9*7 spatial positions per batch

typedef __attribute__((ext_vector_type(8))) short bf16x8;  // 8 bf16 in 4 VGPRs
typedef __attribute__((ext_vector_type(4))) float f32x4;

// R1-R5 lesson: per-thread fp32 VALU for the 64x64 layer is stuck at ~2.2x
// instruction bloat (RA pathology, 310 us floor ~126 us). Pivot: bf16-split
// MFMA (hi+lo, 3 products => fp32-grade precision) for h1 x W2^T.
// M=B*63 pos, N=64, K=64 via mfma_f32_16x16x32_bf16; b2 baked into C-init;
// relu+W3 in epilogue with 16-lane shfl_xor reduction.
__global__ __launch_bounds__(BLOCK_SIZE) void carnet_mfma(
    const float* __restrict__ x,      // (B, 9, 7) flat
    const int*   __restrict__ adj,    // (B, 45)
    const float* __restrict__ ctx,    // (B, 45)
    const float* __restrict__ gcn_W,  // (7, 7)
    const float* __restrict__ gcn_b,  // (7)
    const float* __restrict__ ctx_W,  // (45, 63)
    const float* __restrict__ ctx_b,  // (63)
    const float* __restrict__ W1,     // (64, 2)
    const float* __restrict__ b1,     // (64)
    const float* __restrict__ W2,     // (64, 64)
    const float* __restrict__ b2,     // (64)
    const float* __restrict__ W3,     // (2, 64)
    const float* __restrict__ b3,     // (2)
    float* __restrict__ out,          // (B, 2, 9, 7) flat
    int total)
{
    // h1 hi/lo bf16 planes. Row stride 72 shorts = 144 B: 16B-aligned for
    // ds_read_b128, and 36-dword stride => 2 lanes/bank (free aliasing).
    __shared__ short hh[BLOCK_SIZE][72];
    __shared__ short hl[BLOCK_SIZE][72];

    const int t   = threadIdx.x;
    const int tid = blockIdx.x * BLOCK_SIZE + t;
    const int tidc = tid < total ? tid : total - 1;   // safe clamp (no tail in practice)
    const int b = tidc / NPOS;
    const int p = tidc - b * NPOS;
    const int n = p / 7;
    const int f = p - n * 7;

    // ================= PHASE 1: per-thread z, c, h1 -> LDS ==============
    const int* ab = adj + b * 45;
    uint64_t am = 0;
#pragma unroll
    for (int i = 0; i < 45; ++i)
        am |= (uint64_t)(ab[i] != 0) << i;

    float d[9];
#pragma unroll
    for (int i = 0; i < 9; ++i) {
        const int s = 9 * i - (i * (i - 1)) / 2;
        const int w = 8 - i;
        const uint64_t bits = (am >> (s + 1)) & ((1ull << w) - 1ull);
        const int rs = 1 + __popcll(bits);
        d[i] = __frsqrt_rn((float)rs);
    }

    const float* xb = x + b * 63;
    const int sn = 9 * n - (n * (n - 1)) / 2;
    float zacc = 0.f;
#pragma unroll
    for (int m = 0; m < 9; ++m) {
        int sh = sn + m - n;
        sh = sh < 0 ? 0 : sh;
        const bool conn = (m == n) || ((m > n) && ((am >> sh) & 1ull));
        const float wm = conn ? d[m] : 0.f;
        float ym = 0.f;
#pragma unroll
        for (int k = 0; k < 7; ++k)
            ym = fmaf(xb[m * 7 + k], gcn_W[k * 7 + f], ym);
        zacc = fmaf(wm, ym, zacc);
    }
    const float zv = fmaf(d[n], zacc, gcn_b[f]);

    const float* cb = ctx + b * 45;
    float cacc = ctx_b[p];
#pragma unroll
    for (int q = 0; q < 45; ++q)
        cacc = fmaf(cb[q], ctx_W[q * 63 + p], cacc);
    const float cvv = fmaxf(cacc, 0.f);

    // h1 = relu(W1*[z,c]+b1), split into bf16 hi (truncate) + lo planes.
#pragma unroll
    for (int kc = 0; kc < 8; ++kc) {
        bf16x8 vhi, vlo;
#pragma unroll
        for (int j = 0; j < 8; ++j) {
            const int o = kc * 8 + j;
            const float h = fmaxf(fmaf(W1[2*o], zv, fmaf(W1[2*o+1], cvv, b1[o])), 0.f);
            const unsigned u = __float_as_uint(h);
            vhi[j] = (short)(u >> 16);
            const float l = h - __uint_as_float(u & 0xFFFF0000u);
            vlo[j] = (short)(__float_as_uint(l) >> 16);
        }
        *(bf16x8*)&hh[t][kc * 8] = vhi;
        *(bf16x8*)&hl[t][kc * 8] = vlo;
    }

    __syncthreads();

    // ================= PHASE 2: MFMA over 4 M-tiles per wave ============
    const int lane = t & 63;
    const int wav  = t >> 6;          // 0 or 1
    const int cl   = lane & 15;       // column within tile (= och % 16, = pos row for A)
    const int quad = lane >> 4;       // k-octet selector / C row group

    // B fragments: B[k][n] = W2[n][k]; lane holds n=cl, k=kq*32+quad*8+j.
#define DEF_B(nt, kq)                                                         \
    bf16x8 bh##nt##kq, bl##nt##kq; {                                          \
        const float* wp = W2 + ((nt)*16 + cl) * 64 + (kq)*32 + quad * 8;      \
        _Pragma("unroll")                                                     \
        for (int j = 0; j < 8; ++j) {                                         \
            const float w = wp[j];                                            \
            const unsigned u = __float_as_uint(w);                            \
            bh##nt##kq[j] = (short)(u >> 16);                                 \
            const float l = w - __uint_as_float(u & 0xFFFF0000u);             \
            bl##nt##kq[j] = (short)(__float_as_uint(l) >> 16);                \
        } }
    DEF_B(0,0) DEF_B(0,1) DEF_B(1,0) DEF_B(1,1)
    DEF_B(2,0) DEF_B(2,1) DEF_B(3,0) DEF_B(3,1)
#undef DEF_B

    const float b2v0 = b2[cl],      b2v1 = b2[16 + cl];
    const float b2v2 = b2[32 + cl], b2v3 = b2[48 + cl];
    const float w3a0 = W3[cl],      w3a1 = W3[16 + cl];
    const float w3a2 = W3[32 + cl], w3a3 = W3[48 + cl];
    const float w3b0 = W3[64 + cl], w3b1 = W3[80 + cl];
    const float w3b2 = W3[96 + cl], w3b3 = W3[112 + cl];
    const float b30 = b3[0], b31 = b3[1];

#pragma unroll
    for (int i = 0; i < 4; ++i) {
        const int mt   = wav * 4 + i;
        const int row0 = mt * 16 + cl;
        const short* hhr = &hh[0][0] + row0 * 72 + quad * 8;
        const short* hlr = &hl[0][0] + row0 * 72 + quad * 8;
        const bf16x8 ah0 = *(const bf16x8*)(hhr);
        const bf16x8 ah1 = *(const bf16x8*)(hhr + 32);
        const bf16x8 al0 = *(const bf16x8*)(hlr);
        const bf16x8 al1 = *(const bf16x8*)(hlr + 32);

        f32x4 acc0 = {b2v0, b2v0, b2v0, b2v0};
        f32x4 acc1 = {b2v1, b2v1, b2v1, b2v1};
        f32x4 acc2 = {b2v2, b2v2, b2v2, b2v2};
        f32x4 acc3 = {b2v3, b2v3, b2v3, b2v3};

#define STEP(nt)                                                                      \
        acc##nt = __builtin_amdgcn_mfma_f32_16x16x32_bf16(ah0, bh##nt##0, acc##nt, 0, 0, 0); \
        acc##nt = __builtin_amdgcn_mfma_f32_16x16x32_bf16(al0, bh##nt##0, acc##nt, 0, 0, 0); \
        acc##nt = __builtin_amdgcn_mfma_f32_16x16x32_bf16(ah0, bl##nt##0, acc##nt, 0, 0, 0); \
        acc##nt = __builtin_amdgcn_mfma_f32_16x16x32_bf16(ah1, bh##nt##1, acc##nt, 0, 0, 0); \
        acc##nt = __builtin_amdgcn_mfma_f32_16x16x32_bf16(al1, bh##nt##1, acc##nt, 0, 0, 0); \
        acc##nt = __builtin_amdgcn_mfma_f32_16x16x32_bf16(ah1, bl##nt##1, acc##nt, 0, 0, 0);
        STEP(0) STEP(1) STEP(2) STEP(3)
#undef STEP

        // Epilogue: h2 = relu(acc) (C layout: col=cl, row=quad*4+reg);
        // q0/q1 = per-col partial of W3 dot; reduce over 16 cols via shfl_xor.
        const int posBase = blockIdx.x * BLOCK_SIZE + mt * 16;
#define REDST(reg) {                                                          \
        const float h20 = fmaxf(acc0[reg], 0.f);                              \
        const float h21 = fmaxf(acc1[reg], 0.f);                              \
        const float h22 = fmaxf(acc2[reg], 0.f);                              \
        const float h23 = fmaxf(acc3[reg], 0.f);                              \
        float q0 = fmaf(h23, w3a3, fmaf(h22, w3a2, fmaf(h21, w3a1, h20 * w3a0))); \
        float q1 = fmaf(h23, w3b3, fmaf(h22, w3b2, fmaf(h21, w3b1, h20 * w3b0))); \
        q0 += __shfl_xor(q0, 1); q0 += __shfl_xor(q0, 2);                     \
        q0 += __shfl_xor(q0, 4); q0 += __shfl_xor(q0, 8);                     \
        q1 += __shfl_xor(q1, 1); q1 += __shfl_xor(q1, 2);                     \
        q1 += __shfl_xor(q1, 4); q1 += __shfl_xor(q1, 8);                     \
        const int pos = posBase + quad * 4 + (reg);                           \
        if (cl == 0 && pos < total) {                                         \
            const int bb = pos / NPOS;                                        \
            const int pp = pos - bb * NPOS;                                   \
            out[bb * 126 + pp]      = q0 + b30;                               \
            out[bb * 126 + 63 + pp] = q1 + b31;                               \
        } }
        REDST(0) REDST(1) REDST(2) REDST(3)
#undef REDST
    }
}

extern "C" void kernel_launch(void* const* d_in, const int* in_sizes, int n_in,
                              void* d_out, int out_size, void* d_ws, size_t ws_size,
                              hipStream_t stream) {
    const float* x     = (const float*)d_in[0];
    const int*   adj   = (const int*)  d_in[1];
    const float* ctx   = (const float*)d_in[2];
    const float* gcn_W = (const float*)d_in[3];
    const float* gcn_b = (const float*)d_in[4];
    const float* ctx_W = (const float*)d_in[5];
    const float* ctx_b = (const float*)d_in[6];
    const float* W1    = (const float*)d_in[7];
    const float* b1    = (const float*)d_in[8];
    const float* W2    = (const float*)d_in[9];
    const float* b2    = (const float*)d_in[10];
    const float* W3    = (const float*)d_in[11];
    const float* b3    = (const float*)d_in[12];
    float* out = (float*)d_out;

    const int total = in_sizes[0];  // B * 63 positions (exactly divisible by 128)
    const int grid = (total + BLOCK_SIZE - 1) / BLOCK_SIZE;
    carnet_mfma<<<grid, BLOCK_SIZE, 0, stream>>>(
        x, adj, ctx, gcn_W, gcn_b, ctx_W, ctx_b,
        W1, b1, W2, b2, W3, b3, out, total);
}

// Round 7
// 265.050 us; speedup vs baseline: 3.0501x; 1.0416x over previous
//
#include <hip/hip_runtime.h>
#include <cstdint>

#define BLOCK_SIZE 256
#define NPOS 63   // 9*7 spatial positions per batch

typedef __attribute__((ext_vector_type(8))) short bf16x8;  // 8 bf16 in 4 VGPRs
typedef __attribute__((ext_vector_type(4))) float f32x4;

// Pre-kernel: split W2 (64x64 fp32) into bf16 hi/lo planes in d_ws once per
// launch (R6 did this per-block: ~320 VALU x 16128 blocks wasted).
__global__ __launch_bounds__(256) void w2split_kernel(
    const float* __restrict__ W2, short* __restrict__ w2h, short* __restrict__ w2l)
{
    const int i = blockIdx.x * 256 + threadIdx.x;
    if (i < 4096) {
        const float w = W2[i];
        const unsigned u = __float_as_uint(w);
        w2h[i] = (short)(u >> 16);
        const float l = w - __uint_as_float(u & 0xFFFF0000u);
        w2l[i] = (short)(__float_as_uint(l) >> 16);
    }
}

// R6 -> R7: same proven MFMA mappings, but NO h1 LDS round-trip. h1 is rank-2
// in (z,c), so each lane builds its A-fragment directly from z,c obtained via
// intra-wave __shfl (each wave's 4 M-tiles are its own 64 positions). LDS=0,
// no barrier; occupancy becomes VGPR-limited instead of LDS-capped (was 22%).
__global__ __launch_bounds__(BLOCK_SIZE) void carnet_mfma(
    const float* __restrict__ x,      // (B, 9, 7) flat
    const int*   __restrict__ adj,    // (B, 45)
    const float* __restrict__ ctx,    // (B, 45)
    const float* __restrict__ gcn_W,  // (7, 7)
    const float* __restrict__ gcn_b,  // (7)
    const float* __restrict__ ctx_W,  // (45, 63)
    const float* __restrict__ ctx_b,  // (63)
    const float* __restrict__ W1,     // (64, 2)
    const float* __restrict__ b1,     // (64)
    const short* __restrict__ w2h,    // (64, 64) bf16 hi plane (from pre-kernel)
    const short* __restrict__ w2l,    // (64, 64) bf16 lo plane
    const float* __restrict__ b2,     // (64)
    const float* __restrict__ W3,     // (2, 64)
    const float* __restrict__ b3,     // (2)
    float* __restrict__ out,          // (B, 2, 9, 7) flat
    int total)
{
    const int t   = threadIdx.x;
    const int tid = blockIdx.x * BLOCK_SIZE + t;
    const int tidc = tid < total ? tid : total - 1;   // no tail in practice
    const int b = tidc / NPOS;
    const int p = tidc - b * NPOS;
    const int n = p / 7;
    const int f = p - n * 7;

    // ================= PHASE 1: per-thread z, c (proven R1 code) ========
    const int* ab = adj + b * 45;
    uint64_t am = 0;
#pragma unroll
    for (int i = 0; i < 45; ++i)
        am |= (uint64_t)(ab[i] != 0) << i;

    float d[9];
#pragma unroll
    for (int i = 0; i < 9; ++i) {
        const int s = 9 * i - (i * (i - 1)) / 2;
        const int w = 8 - i;
        const uint64_t bits = (am >> (s + 1)) & ((1ull << w) - 1ull);
        const int rs = 1 + __popcll(bits);
        d[i] = __frsqrt_rn((float)rs);
    }

    const float* xb = x + b * 63;
    const int sn = 9 * n - (n * (n - 1)) / 2;
    float zacc = 0.f;
#pragma unroll
    for (int m = 0; m < 9; ++m) {
        int sh = sn + m - n;
        sh = sh < 0 ? 0 : sh;
        const bool conn = (m == n) || ((m > n) && ((am >> sh) & 1ull));
        const float wm = conn ? d[m] : 0.f;
        float ym = 0.f;
#pragma unroll
        for (int k = 0; k < 7; ++k)
            ym = fmaf(xb[m * 7 + k], gcn_W[k * 7 + f], ym);
        zacc = fmaf(wm, ym, zacc);
    }
    const float zv = fmaf(d[n], zacc, gcn_b[f]);

    const float* cb = ctx + b * 45;
    float cacc = ctx_b[p];
#pragma unroll
    for (int q = 0; q < 45; ++q)
        cacc = fmaf(cb[q], ctx_W[q * 63 + p], cacc);
    const float cvv = fmaxf(cacc, 0.f);

    // ================= PHASE 2: MFMA, 4 M-tiles per wave ================
    const int lane = t & 63;
    const int cl   = lane & 15;       // A row within tile / B column (och%16)
    const int quad = lane >> 4;       // k-octet selector / C row group
    const int waveBase = blockIdx.x * BLOCK_SIZE + (t & ~63); // wave's pos base

    // B fragments straight from precomputed planes (16B aligned loads).
#define DEF_B(nt, kq)                                                         \
    const bf16x8 bh##nt##kq = *(const bf16x8*)(w2h + ((nt)*16 + cl)*64 + (kq)*32 + quad*8); \
    const bf16x8 bl##nt##kq = *(const bf16x8*)(w2l + ((nt)*16 + cl)*64 + (kq)*32 + quad*8);
    DEF_B(0,0) DEF_B(0,1) DEF_B(1,0) DEF_B(1,1)
    DEF_B(2,0) DEF_B(2,1) DEF_B(3,0) DEF_B(3,1)
#undef DEF_B

    // Per-lane W1/b1 constants for this lane's 16 k-indices (resident).
    float2 wp0[8], wp1[8];
    float  bb0[8], bb1[8];
#pragma unroll
    for (int j = 0; j < 8; ++j) {
        const int o = quad * 8 + j;
        wp0[j] = *(const float2*)(W1 + 2 * o);
        bb0[j] = b1[o];
        wp1[j] = *(const float2*)(W1 + 2 * (o + 32));
        bb1[j] = b1[o + 32];
    }

    const float b2v0 = b2[cl],      b2v1 = b2[16 + cl];
    const float b2v2 = b2[32 + cl], b2v3 = b2[48 + cl];
    const float w3a0 = W3[cl],      w3a1 = W3[16 + cl];
    const float w3a2 = W3[32 + cl], w3a3 = W3[48 + cl];
    const float w3b0 = W3[64 + cl], w3b1 = W3[80 + cl];
    const float w3b2 = W3[96 + cl], w3b3 = W3[112 + cl];
    const float b30 = b3[0], b31 = b3[1];

#pragma unroll
    for (int i = 0; i < 4; ++i) {
        // z,c of row m = i*16+cl within this wave's 64 positions.
        const float zm = __shfl(zv,  i * 16 + cl);
        const float cm = __shfl(cvv, i * 16 + cl);

        // A fragments computed in-register: h1[k] = relu(w0*z + w1*c + b).
        bf16x8 ah0, al0, ah1, al1;
#pragma unroll
        for (int j = 0; j < 8; ++j) {
            const float h0 = fmaxf(fmaf(wp0[j].x, zm, fmaf(wp0[j].y, cm, bb0[j])), 0.f);
            unsigned u = __float_as_uint(h0);
            ah0[j] = (short)(u >> 16);
            const float l0 = h0 - __uint_as_float(u & 0xFFFF0000u);
            al0[j] = (short)(__float_as_uint(l0) >> 16);

            const float h1v = fmaxf(fmaf(wp1[j].x, zm, fmaf(wp1[j].y, cm, bb1[j])), 0.f);
            u = __float_as_uint(h1v);
            ah1[j] = (short)(u >> 16);
            const float l1 = h1v - __uint_as_float(u & 0xFFFF0000u);
            al1[j] = (short)(__float_as_uint(l1) >> 16);
        }

        f32x4 acc0 = {b2v0, b2v0, b2v0, b2v0};
        f32x4 acc1 = {b2v1, b2v1, b2v1, b2v1};
        f32x4 acc2 = {b2v2, b2v2, b2v2, b2v2};
        f32x4 acc3 = {b2v3, b2v3, b2v3, b2v3};

#define STEP(nt)                                                                      \
        acc##nt = __builtin_amdgcn_mfma_f32_16x16x32_bf16(ah0, bh##nt##0, acc##nt, 0, 0, 0); \
        acc##nt = __builtin_amdgcn_mfma_f32_16x16x32_bf16(al0, bh##nt##0, acc##nt, 0, 0, 0); \
        acc##nt = __builtin_amdgcn_mfma_f32_16x16x32_bf16(ah0, bl##nt##0, acc##nt, 0, 0, 0); \
        acc##nt = __builtin_amdgcn_mfma_f32_16x16x32_bf16(ah1, bh##nt##1, acc##nt, 0, 0, 0); \
        acc##nt = __builtin_amdgcn_mfma_f32_16x16x32_bf16(al1, bh##nt##1, acc##nt, 0, 0, 0); \
        acc##nt = __builtin_amdgcn_mfma_f32_16x16x32_bf16(ah1, bl##nt##1, acc##nt, 0, 0, 0);
        STEP(0) STEP(1) STEP(2) STEP(3)
#undef STEP

        // Epilogue (proven R6): h2=relu(acc) in C layout (col=cl, row=quad*4+reg);
        // W3 dot + 16-lane shfl_xor reduce; lane cl==0 stores.
        const int posBase = waveBase + i * 16;
#define REDST(reg) {                                                          \
        const float h20 = fmaxf(acc0[reg], 0.f);                              \
        const float h21 = fmaxf(acc1[reg], 0.f);                              \
        const float h22 = fmaxf(acc2[reg], 0.f);                              \
        const float h23 = fmaxf(acc3[reg], 0.f);                              \
        float q0 = fmaf(h23, w3a3, fmaf(h22, w3a2, fmaf(h21, w3a1, h20 * w3a0))); \
        float q1 = fmaf(h23, w3b3, fmaf(h22, w3b2, fmaf(h21, w3b1, h20 * w3b0))); \
        q0 += __shfl_xor(q0, 1); q0 += __shfl_xor(q0, 2);                     \
        q0 += __shfl_xor(q0, 4); q0 += __shfl_xor(q0, 8);                     \
        q1 += __shfl_xor(q1, 1); q1 += __shfl_xor(q1, 2);                     \
        q1 += __shfl_xor(q1, 4); q1 += __shfl_xor(q1, 8);                     \
        const int pos = posBase + quad * 4 + (reg);                           \
        if (cl == 0 && pos < total) {                                         \
            const int bb = pos / NPOS;                                        \
            const int pp = pos - bb * NPOS;                                   \
            out[bb * 126 + pp]      = q0 + b30;                               \
            out[bb * 126 + 63 + pp] = q1 + b31;                               \
        } }
        REDST(0) REDST(1) REDST(2) REDST(3)
#undef REDST
    }
}

extern "C" void kernel_launch(void* const* d_in, const int* in_sizes, int n_in,
                              void* d_out, int out_size, void* d_ws, size_t ws_size,
                              hipStream_t stream) {
    const float* x     = (const float*)d_in[0];
    const int*   adj   = (const int*)  d_in[1];
    const float* ctx   = (const float*)d_in[2];
    const float* gcn_W = (const float*)d_in[3];
    const float* gcn_b = (const float*)d_in[4];
    const float* ctx_W = (const float*)d_in[5];
    const float* ctx_b = (const float*)d_in[6];
    const float* W1    = (const float*)d_in[7];
    const float* b1    = (const float*)d_in[8];
    const float* W2    = (const float*)d_in[9];
    const float* b2    = (const float*)d_in[10];
    const float* W3    = (const float*)d_in[11];
    const float* b3    = (const float*)d_in[12];
    float* out = (float*)d_out;

    short* w2h = (short*)d_ws;          // 8 KB
    short* w2l = w2h + 4096;            // 8 KB

    w2split_kernel<<<16, 256, 0, stream>>>(W2, w2h, w2l);

    const int total = in_sizes[0];      // B * 63 = 2064384 (divisible by 256)
    const int grid = (total + BLOCK_SIZE - 1) / BLOCK_SIZE;
    carnet_mfma<<<grid, BLOCK_SIZE, 0, stream>>>(
        x, adj, ctx, gcn_W, gcn_b, ctx_W, ctx_b,
        W1, b1, w2h, w2l, b2, W3, b3, out, total);
}

// Round 8
// 259.757 us; speedup vs baseline: 3.1123x; 1.0204x over previous
//
#include <hip/hip_runtime.h>
#include <cstdint>

#define BLOCK_SIZE 256
#define NPOS 63   // 9*7 spatial positions per batch

typedef __attribute__((ext_vector_type(8))) short bf16x8;  // 8 bf16 in 4 VGPRs
typedef __attribute__((ext_vector_type(4))) float f32x4;

// DPP row-reduction step: v += v[permuted lane within 16-lane row].
// All 4 butterfly steps stay on the VALU pipe (2 cyc) instead of
// ds_bpermute (LDS pipe, ~5.8 cyc tput + 30 cyc latency). R7 post-mortem:
// 256 shfl_xor/thread = ~40% of runtime on the LDS pipe.
template <int CTRL>
__device__ __forceinline__ float dpp_add(float v) {
    const int m = __builtin_amdgcn_update_dpp(0, __float_as_int(v), CTRL, 0xF, 0xF, true);
    return v + __int_as_float(m);
}
__device__ __forceinline__ float row16_sum(float v) {
    v = dpp_add<0xB1>(v);   // quad_perm(1,0,3,2)  = xor 1
    v = dpp_add<0x4E>(v);   // quad_perm(2,3,0,1)  = xor 2
    v = dpp_add<0x124>(v);  // row_ror:4  (sum-of-rotations)
    v = dpp_add<0x128>(v);  // row_ror:8
    return v;               // every lane in the row holds the full sum
}

// Pre-kernel: split W2 (64x64 fp32) into bf16 hi/lo planes in d_ws once.
__global__ __launch_bounds__(256) void w2split_kernel(
    const float* __restrict__ W2, short* __restrict__ w2h, short* __restrict__ w2l)
{
    const int i = blockIdx.x * 256 + threadIdx.x;
    if (i < 4096) {
        const float w = W2[i];
        const unsigned u = __float_as_uint(w);
        w2h[i] = (short)(u >> 16);
        const float l = w - __uint_as_float(u & 0xFFFF0000u);
        w2l[i] = (short)(__float_as_uint(l) >> 16);
    }
}

// R7 -> R8: identical math/mappings; epilogue reduction moved from
// ds_bpermute (shfl_xor) to DPP VALU ops; M-tile loop kept rolled
// (#pragma unroll 1) to shrink code footprint ~4x.
__global__ __launch_bounds__(BLOCK_SIZE) void carnet_mfma(
    const float* __restrict__ x,      // (B, 9, 7) flat
    const int*   __restrict__ adj,    // (B, 45)
    const float* __restrict__ ctx,    // (B, 45)
    const float* __restrict__ gcn_W,  // (7, 7)
    const float* __restrict__ gcn_b,  // (7)
    const float* __restrict__ ctx_W,  // (45, 63)
    const float* __restrict__ ctx_b,  // (63)
    const float* __restrict__ W1,     // (64, 2)
    const float* __restrict__ b1,     // (64)
    const short* __restrict__ w2h,    // (64, 64) bf16 hi plane
    const short* __restrict__ w2l,    // (64, 64) bf16 lo plane
    const float* __restrict__ b2,     // (64)
    const float* __restrict__ W3,     // (2, 64)
    const float* __restrict__ b3,     // (2)
    float* __restrict__ out,          // (B, 2, 9, 7) flat
    int total)
{
    const int t   = threadIdx.x;
    const int tid = blockIdx.x * BLOCK_SIZE + t;
    const int tidc = tid < total ? tid : total - 1;   // no tail in practice
    const int b = tidc / NPOS;
    const int p = tidc - b * NPOS;
    const int n = p / 7;
    const int f = p - n * 7;

    // ================= PHASE 1: per-thread z, c (proven R1 code) ========
    const int* ab = adj + b * 45;
    uint64_t am = 0;
#pragma unroll
    for (int i = 0; i < 45; ++i)
        am |= (uint64_t)(ab[i] != 0) << i;

    float d[9];
#pragma unroll
    for (int i = 0; i < 9; ++i) {
        const int s = 9 * i - (i * (i - 1)) / 2;
        const int w = 8 - i;
        const uint64_t bits = (am >> (s + 1)) & ((1ull << w) - 1ull);
        const int rs = 1 + __popcll(bits);
        d[i] = __frsqrt_rn((float)rs);
    }

    const float* xb = x + b * 63;
    const int sn = 9 * n - (n * (n - 1)) / 2;
    float zacc = 0.f;
#pragma unroll
    for (int m = 0; m < 9; ++m) {
        int sh = sn + m - n;
        sh = sh < 0 ? 0 : sh;
        const bool conn = (m == n) || ((m > n) && ((am >> sh) & 1ull));
        const float wm = conn ? d[m] : 0.f;
        float ym = 0.f;
#pragma unroll
        for (int k = 0; k < 7; ++k)
            ym = fmaf(xb[m * 7 + k], gcn_W[k * 7 + f], ym);
        zacc = fmaf(wm, ym, zacc);
    }
    const float zv = fmaf(d[n], zacc, gcn_b[f]);

    const float* cb = ctx + b * 45;
    float cacc = ctx_b[p];
#pragma unroll
    for (int q = 0; q < 45; ++q)
        cacc = fmaf(cb[q], ctx_W[q * 63 + p], cacc);
    const float cvv = fmaxf(cacc, 0.f);

    // ================= PHASE 2: MFMA, 4 M-tiles per wave ================
    const int lane = t & 63;
    const int cl   = lane & 15;       // A row within tile / B column (och%16)
    const int quad = lane >> 4;       // k-octet selector / C row group
    const int waveBase = blockIdx.x * BLOCK_SIZE + (t & ~63); // wave's pos base

    // B fragments straight from precomputed planes (16B aligned loads).
#define DEF_B(nt, kq)                                                         \
    const bf16x8 bh##nt##kq = *(const bf16x8*)(w2h + ((nt)*16 + cl)*64 + (kq)*32 + quad*8); \
    const bf16x8 bl##nt##kq = *(const bf16x8*)(w2l + ((nt)*16 + cl)*64 + (kq)*32 + quad*8);
    DEF_B(0,0) DEF_B(0,1) DEF_B(1,0) DEF_B(1,1)
    DEF_B(2,0) DEF_B(2,1) DEF_B(3,0) DEF_B(3,1)
#undef DEF_B

    // Per-lane W1/b1 constants for this lane's 16 k-indices (resident).
    float2 wp0[8], wp1[8];
    float  bb0[8], bb1[8];
#pragma unroll
    for (int j = 0; j < 8; ++j) {
        const int o = quad * 8 + j;
        wp0[j] = *(const float2*)(W1 + 2 * o);
        bb0[j] = b1[o];
        wp1[j] = *(const float2*)(W1 + 2 * (o + 32));
        bb1[j] = b1[o + 32];
    }

    const float b2v0 = b2[cl],      b2v1 = b2[16 + cl];
    const float b2v2 = b2[32 + cl], b2v3 = b2[48 + cl];
    const float w3a0 = W3[cl],      w3a1 = W3[16 + cl];
    const float w3a2 = W3[32 + cl], w3a3 = W3[48 + cl];
    const float w3b0 = W3[64 + cl], w3b1 = W3[80 + cl];
    const float w3b2 = W3[96 + cl], w3b3 = W3[112 + cl];
    const float b30 = b3[0], b31 = b3[1];

#pragma unroll 1
    for (int i = 0; i < 4; ++i) {
        // z,c of row m = i*16+cl within this wave's 64 positions.
        const float zm = __shfl(zv,  i * 16 + cl);
        const float cm = __shfl(cvv, i * 16 + cl);

        // A fragments computed in-register: h1[k] = relu(w0*z + w1*c + b).
        bf16x8 ah0, al0, ah1, al1;
#pragma unroll
        for (int j = 0; j < 8; ++j) {
            const float h0 = fmaxf(fmaf(wp0[j].x, zm, fmaf(wp0[j].y, cm, bb0[j])), 0.f);
            unsigned u = __float_as_uint(h0);
            ah0[j] = (short)(u >> 16);
            const float l0 = h0 - __uint_as_float(u & 0xFFFF0000u);
            al0[j] = (short)(__float_as_uint(l0) >> 16);

            const float h1v = fmaxf(fmaf(wp1[j].x, zm, fmaf(wp1[j].y, cm, bb1[j])), 0.f);
            u = __float_as_uint(h1v);
            ah1[j] = (short)(u >> 16);
            const float l1 = h1v - __uint_as_float(u & 0xFFFF0000u);
            al1[j] = (short)(__float_as_uint(l1) >> 16);
        }

        f32x4 acc0 = {b2v0, b2v0, b2v0, b2v0};
        f32x4 acc1 = {b2v1, b2v1, b2v1, b2v1};
        f32x4 acc2 = {b2v2, b2v2, b2v2, b2v2};
        f32x4 acc3 = {b2v3, b2v3, b2v3, b2v3};

#define STEP(nt)                                                                      \
        acc##nt = __builtin_amdgcn_mfma_f32_16x16x32_bf16(ah0, bh##nt##0, acc##nt, 0, 0, 0); \
        acc##nt = __builtin_amdgcn_mfma_f32_16x16x32_bf16(al0, bh##nt##0, acc##nt, 0, 0, 0); \
        acc##nt = __builtin_amdgcn_mfma_f32_16x16x32_bf16(ah0, bl##nt##0, acc##nt, 0, 0, 0); \
        acc##nt = __builtin_amdgcn_mfma_f32_16x16x32_bf16(ah1, bh##nt##1, acc##nt, 0, 0, 0); \
        acc##nt = __builtin_amdgcn_mfma_f32_16x16x32_bf16(al1, bh##nt##1, acc##nt, 0, 0, 0); \
        acc##nt = __builtin_amdgcn_mfma_f32_16x16x32_bf16(ah1, bl##nt##1, acc##nt, 0, 0, 0);
        STEP(0) STEP(1) STEP(2) STEP(3)
#undef STEP

        // Epilogue: h2 = relu(acc) in C layout (col=cl, row=quad*4+reg);
        // W3 dot per lane, then 16-lane DPP row reduction; lane cl==0 stores.
        const int posBase = waveBase + i * 16;
#define REDST(reg) {                                                          \
        const float h20 = fmaxf(acc0[reg], 0.f);                              \
        const float h21 = fmaxf(acc1[reg], 0.f);                              \
        const float h22 = fmaxf(acc2[reg], 0.f);                              \
        const float h23 = fmaxf(acc3[reg], 0.f);                              \
        float q0 = fmaf(h23, w3a3, fmaf(h22, w3a2, fmaf(h21, w3a1, h20 * w3a0))); \
        float q1 = fmaf(h23, w3b3, fmaf(h22, w3b2, fmaf(h21, w3b1, h20 * w3b0))); \
        q0 = row16_sum(q0);                                                   \
        q1 = row16_sum(q1);                                                   \
        const int pos = posBase + quad * 4 + (reg);                           \
        if (cl == 0 && pos < total) {                                         \
            const int bb = pos / NPOS;                                        \
            const int pp = pos - bb * NPOS;                                   \
            out[bb * 126 + pp]      = q0 + b30;                               \
            out[bb * 126 + 63 + pp] = q1 + b31;                               \
        } }
        REDST(0) REDST(1) REDST(2) REDST(3)
#undef REDST
    }
}

extern "C" void kernel_launch(void* const* d_in, const int* in_sizes, int n_in,
                              void* d_out, int out_size, void* d_ws, size_t ws_size,
                              hipStream_t stream) {
    const float* x     = (const float*)d_in[0];
    const int*   adj   = (const int*)  d_in[1];
    const float* ctx   = (const float*)d_in[2];
    const float* gcn_W = (const float*)d_in[3];
    const float* gcn_b = (const float*)d_in[4];
    const float* ctx_W = (const float*)d_in[5];
    const float* ctx_b = (const float*)d_in[6];
    const float* W1    = (const float*)d_in[7];
    const float* b1    = (const float*)d_in[8];
    const float* W2    = (const float*)d_in[9];
    const float* b2    = (const float*)d_in[10];
    const float* W3    = (const float*)d_in[11];
    const float* b3    = (const float*)d_in[12];
    float* out = (float*)d_out;

    short* w2h = (short*)d_ws;          // 8 KB
    short* w2l = w2h + 4096;            // 8 KB

    w2split_kernel<<<16, 256, 0, stream>>>(W2, w2h, w2l);

    const int total = in_sizes[0];      // B * 63 = 2064384 (divisible by 256)
    const int grid = (total + BLOCK_SIZE - 1) / BLOCK_SIZE;
    carnet_mfma<<<grid, BLOCK_SIZE, 0, stream>>>(
        x, adj, ctx, gcn_W, gcn_b, ctx_W, ctx_b,
        W1, b1, w2h, w2l, b2, W3, b3, out, total);
}

// Round 9
// 240.389 us; speedup vs baseline: 3.3630x; 1.0806x over previous
//
#include <hip/hip_runtime.h>
#include <cstdint>

#define BLOCK_SIZE 256
#define NPOS 63   // 9*7 spatial positions per batch

typedef __attribute__((ext_vector_type(8))) short bf16x8;       // 8 bf16, 4 VGPRs
typedef __attribute__((ext_vector_type(4))) float f32x4;
typedef __attribute__((ext_vector_type(4))) unsigned int uint4v;

// DPP 16-lane row reduction (VALU pipe, no LDS) — proven R8.
template <int CTRL>
__device__ __forceinline__ float dpp_add(float v) {
    const int m = __builtin_amdgcn_update_dpp(0, __float_as_int(v), CTRL, 0xF, 0xF, true);
    return v + __int_as_float(m);
}
__device__ __forceinline__ float row16_sum(float v) {
    v = dpp_add<0xB1>(v);   // quad_perm xor1
    v = dpp_add<0x4E>(v);   // quad_perm xor2
    v = dpp_add<0x124>(v);  // row_ror:4
    v = dpp_add<0x128>(v);  // row_ror:8
    return v;               // every lane in the 16-lane row holds the sum
}

// pack hi16(ha):hi16(hb) -> one dword in ONE v_perm_b32 (bytes: [0,1]=S1[2,3], [2,3]=S0[2,3])
__device__ __forceinline__ unsigned pack_hi16(float ha, float hb) {
    return __builtin_amdgcn_perm(__float_as_uint(hb), __float_as_uint(ha), 0x07060302u);
}

// Pre-kernel: split W2 (64x64 fp32) into bf16 hi/lo planes in d_ws once.
__global__ __launch_bounds__(256) void w2split_kernel(
    const float* __restrict__ W2, short* __restrict__ w2h, short* __restrict__ w2l)
{
    const int i = blockIdx.x * 256 + threadIdx.x;
    if (i < 4096) {
        const float w = W2[i];
        const unsigned u = __float_as_uint(w);
        w2h[i] = (short)(u >> 16);
        const float l = w - __uint_as_float(u & 0xFFFF0000u);
        w2l[i] = (short)(__float_as_uint(l) >> 16);
    }
}

// R8 -> R9: ONE WAVE = ONE BATCH (63 positions + 1 dummy lane).
//  - adj/ctx/x become wave-uniform -> scalar loads; mask in SALU, once.
//  - y = x . gcn_W computed once per (m,f) on lane m*7+f, gathered via shfl
//    (was 63 FMA/thread with 9x redundancy).
//  - epilogue addressing: out + b*126 + pp, no per-store division.
//  - A-fragment hi/lo packing via v_perm_b32 (1 op per pair).
// MFMA mappings + split-bf16 numerics bit-identical to R6-R8 (proven).
__global__ __launch_bounds__(BLOCK_SIZE) void carnet_mfma(
    const float* __restrict__ x,      // (B, 9, 7) flat
    const int*   __restrict__ adj,    // (B, 45)
    const float* __restrict__ ctx,    // (B, 45)
    const float* __restrict__ gcn_W,  // (7, 7)
    const float* __restrict__ gcn_b,  // (7)
    const float* __restrict__ ctx_W,  // (45, 63)
    const float* __restrict__ ctx_b,  // (63)
    const float* __restrict__ W1,     // (64, 2)
    const float* __restrict__ b1,     // (64)
    const short* __restrict__ w2h,    // (64, 64) bf16 hi plane
    const short* __restrict__ w2l,    // (64, 64) bf16 lo plane
    const float* __restrict__ b2,     // (64)
    const float* __restrict__ W3,     // (2, 64)
    const float* __restrict__ b3,     // (2)
    float* __restrict__ out,          // (B, 2, 9, 7) flat
    int nbatch)
{
    const int t    = threadIdx.x;
    const int lane = t & 63;
    const int b    = __builtin_amdgcn_readfirstlane(blockIdx.x * 4 + (t >> 6));
    if (b >= nbatch) return;

    const int p = lane < 63 ? lane : 62;   // lane 63 duplicates position 62
    const int n = p / 7;
    const int f = p - n * 7;

    // ---- adjacency mask + degrees (wave-uniform: s_load + SALU) ----
    const int* ab = adj + b * 45;
    uint64_t am = 0;
#pragma unroll
    for (int i = 0; i < 45; ++i)
        am |= (uint64_t)(ab[i] != 0) << i;

    float d[9];
#pragma unroll
    for (int i = 0; i < 9; ++i) {
        const int s = 9 * i - (i * (i - 1)) / 2;
        const int w = 8 - i;
        const uint64_t bits = (am >> (s + 1)) & ((1ull << w) - 1ull);
        d[i] = __frsqrt_rn((float)(1 + __popcll(bits)));
    }

    // ---- y[m][f] once per (m,f) on lane m*7+f; gather for z ----
    const float* xb = x + b * 63;
    float yv = 0.f;
#pragma unroll
    for (int k = 0; k < 7; ++k)
        yv = fmaf(xb[n * 7 + k], gcn_W[k * 7 + f], yv);

    float zt = 0.f;
    const int snn = 9 * n - (n * (n - 1)) / 2 - n;   // sn - n
#pragma unroll
    for (int m = 0; m < 9; ++m) {
        const float ym = __shfl(yv, m * 7 + f);      // y[m][f] from lane m*7+f
        int sh = snn + m;
        sh = sh < 0 ? 0 : sh;
        const bool conn = (m == n) || ((m > n) && ((am >> sh) & 1ull));
        zt = fmaf(conn ? d[m] : 0.f, ym, zt);
    }
    const float zv = fmaf(d[n], zt, gcn_b[f]);

    // ---- c[p] = relu(ctx . ctx_W[:,p] + ctx_b[p]); ctx[q] is s_load ----
    const float* cb = ctx + b * 45;
    float cacc = ctx_b[p];
#pragma unroll
    for (int q = 0; q < 45; ++q)
        cacc = fmaf(cb[q], ctx_W[q * 63 + p], cacc);
    const float cvv = fmaxf(cacc, 0.f);

    // ================= PHASE 2: MFMA, 4 M-tiles per wave ================
    const int cl   = lane & 15;       // A row within tile / B column (och%16)
    const int quad = lane >> 4;       // k-octet selector / C row group

    // B fragments straight from precomputed planes (16B aligned loads).
#define DEF_B(nt, kq)                                                         \
    const bf16x8 bh##nt##kq = *(const bf16x8*)(w2h + ((nt)*16 + cl)*64 + (kq)*32 + quad*8); \
    const bf16x8 bl##nt##kq = *(const bf16x8*)(w2l + ((nt)*16 + cl)*64 + (kq)*32 + quad*8);
    DEF_B(0,0) DEF_B(0,1) DEF_B(1,0) DEF_B(1,1)
    DEF_B(2,0) DEF_B(2,1) DEF_B(3,0) DEF_B(3,1)
#undef DEF_B

    // Per-lane W1/b1 constants for this lane's 16 k-indices (resident).
    float2 wp0[8], wp1[8];
    float  bb0[8], bb1[8];
#pragma unroll
    for (int j = 0; j < 8; ++j) {
        const int o = quad * 8 + j;
        wp0[j] = *(const float2*)(W1 + 2 * o);
        bb0[j] = b1[o];
        wp1[j] = *(const float2*)(W1 + 2 * (o + 32));
        bb1[j] = b1[o + 32];
    }

    const float b2v0 = b2[cl],      b2v1 = b2[16 + cl];
    const float b2v2 = b2[32 + cl], b2v3 = b2[48 + cl];
    const float w3a0 = W3[cl],      w3a1 = W3[16 + cl];
    const float w3a2 = W3[32 + cl], w3a3 = W3[48 + cl];
    const float w3b0 = W3[64 + cl], w3b1 = W3[80 + cl];
    const float w3b2 = W3[96 + cl], w3b3 = W3[112 + cl];
    const float b30 = b3[0], b31 = b3[1];
    float* __restrict__ ob = out + b * 126;

#pragma unroll 1
    for (int i = 0; i < 4; ++i) {
        // z,c of row m = i*16+cl within this wave's 64 (=63+pad) positions.
        const float zm = __shfl(zv,  i * 16 + cl);
        const float cm = __shfl(cvv, i * 16 + cl);

        // A fragments: h1[k] = relu(w0*z + w1*c + b); hi=trunc16, lo=residual.
        uint4v ph0, pl0, ph1, pl1;
#pragma unroll
        for (int jj = 0; jj < 4; ++jj) {
            float ha = fmaxf(fmaf(wp0[2*jj].x,   zm, fmaf(wp0[2*jj].y,   cm, bb0[2*jj])),   0.f);
            float hb = fmaxf(fmaf(wp0[2*jj+1].x, zm, fmaf(wp0[2*jj+1].y, cm, bb0[2*jj+1])), 0.f);
            ph0[jj] = pack_hi16(ha, hb);
            float la = ha - __uint_as_float(__float_as_uint(ha) & 0xFFFF0000u);
            float lb = hb - __uint_as_float(__float_as_uint(hb) & 0xFFFF0000u);
            pl0[jj] = pack_hi16(la, lb);

            ha = fmaxf(fmaf(wp1[2*jj].x,   zm, fmaf(wp1[2*jj].y,   cm, bb1[2*jj])),   0.f);
            hb = fmaxf(fmaf(wp1[2*jj+1].x, zm, fmaf(wp1[2*jj+1].y, cm, bb1[2*jj+1])), 0.f);
            ph1[jj] = pack_hi16(ha, hb);
            la = ha - __uint_as_float(__float_as_uint(ha) & 0xFFFF0000u);
            lb = hb - __uint_as_float(__float_as_uint(hb) & 0xFFFF0000u);
            pl1[jj] = pack_hi16(la, lb);
        }
        const bf16x8 ah0 = __builtin_bit_cast(bf16x8, ph0);
        const bf16x8 al0 = __builtin_bit_cast(bf16x8, pl0);
        const bf16x8 ah1 = __builtin_bit_cast(bf16x8, ph1);
        const bf16x8 al1 = __builtin_bit_cast(bf16x8, pl1);

        f32x4 acc0 = {b2v0, b2v0, b2v0, b2v0};
        f32x4 acc1 = {b2v1, b2v1, b2v1, b2v1};
        f32x4 acc2 = {b2v2, b2v2, b2v2, b2v2};
        f32x4 acc3 = {b2v3, b2v3, b2v3, b2v3};

#define STEP(nt)                                                                      \
        acc##nt = __builtin_amdgcn_mfma_f32_16x16x32_bf16(ah0, bh##nt##0, acc##nt, 0, 0, 0); \
        acc##nt = __builtin_amdgcn_mfma_f32_16x16x32_bf16(al0, bh##nt##0, acc##nt, 0, 0, 0); \
        acc##nt = __builtin_amdgcn_mfma_f32_16x16x32_bf16(ah0, bl##nt##0, acc##nt, 0, 0, 0); \
        acc##nt = __builtin_amdgcn_mfma_f32_16x16x32_bf16(ah1, bh##nt##1, acc##nt, 0, 0, 0); \
        acc##nt = __builtin_amdgcn_mfma_f32_16x16x32_bf16(al1, bh##nt##1, acc##nt, 0, 0, 0); \
        acc##nt = __builtin_amdgcn_mfma_f32_16x16x32_bf16(ah1, bl##nt##1, acc##nt, 0, 0, 0);
        STEP(0) STEP(1) STEP(2) STEP(3)
#undef STEP

        // Epilogue: h2 = relu(acc) (C layout: col=cl, row=quad*4+reg);
        // W3 dot per lane, DPP 16-lane reduction, lane cl==0 stores.
        const int ppBase = i * 16 + quad * 4;
#define REDST(reg) {                                                          \
        const float h20 = fmaxf(acc0[reg], 0.f);                              \
        const float h21 = fmaxf(acc1[reg], 0.f);                              \
        const float h22 = fmaxf(acc2[reg], 0.f);                              \
        const float h23 = fmaxf(acc3[reg], 0.f);                              \
        float q0 = fmaf(h23, w3a3, fmaf(h22, w3a2, fmaf(h21, w3a1, h20 * w3a0))); \
        float q1 = fmaf(h23, w3b3, fmaf(h22, w3b2, fmaf(h21, w3b1, h20 * w3b0))); \
        q0 = row16_sum(q0);                                                   \
        q1 = row16_sum(q1);                                                   \
        const int pp = ppBase + (reg);                                        \
        if (cl == 0 && pp < NPOS) {                                           \
            ob[pp]        = q0 + b30;                                         \
            ob[NPOS + pp] = q1 + b31;                                         \
        } }
        REDST(0) REDST(1) REDST(2) REDST(3)
#undef REDST
    }
}

extern "C" void kernel_launch(void* const* d_in, const int* in_sizes, int n_in,
                              void* d_out, int out_size, void* d_ws, size_t ws_size,
                              hipStream_t stream) {
    const float* x     = (const float*)d_in[0];
    const int*   adj   = (const int*)  d_in[1];
    const float* ctx   = (const float*)d_in[2];
    const float* gcn_W = (const float*)d_in[3];
    const float* gcn_b = (const float*)d_in[4];
    const float* ctx_W = (const float*)d_in[5];
    const float* ctx_b = (const float*)d_in[6];
    const float* W1    = (const float*)d_in[7];
    const float* b1    = (const float*)d_in[8];
    const float* W2    = (const float*)d_in[9];
    const float* b2    = (const float*)d_in[10];
    const float* W3    = (const float*)d_in[11];
    const float* b3    = (const float*)d_in[12];
    float* out = (float*)d_out;

    short* w2h = (short*)d_ws;          // 8 KB
    short* w2l = w2h + 4096;            // 8 KB

    w2split_kernel<<<16, 256, 0, stream>>>(W2, w2h, w2l);

    const int nbatch = in_sizes[1] / 45;            // B = 32768
    const int grid = (nbatch + 3) / 4;              // 4 batches (waves) per block
    carnet_mfma<<<grid, BLOCK_SIZE, 0, stream>>>(
        x, adj, ctx, gcn_W, gcn_b, ctx_W, ctx_b,
        W1, b1, w2h, w2l, b2, W3, b3, out, nbatch);
}

// Round 10
// 186.464 us; speedup vs baseline: 4.3356x; 1.2892x over previous
//
#include <hip/hip_runtime.h>
#include <cstdint>

#define BLOCK_SIZE 256
#define NPOS 63   // 9*7 spatial positions per batch

typedef __attribute__((ext_vector_type(8))) short bf16x8;       // 8 bf16, 4 VGPRs
typedef __attribute__((ext_vector_type(4))) float f32x4;
typedef __attribute__((ext_vector_type(4))) unsigned int uint4v;

// DPP 16-lane row reduction (VALU pipe, no LDS) — proven R8/R9.
template <int CTRL>
__device__ __forceinline__ float dpp_add(float v) {
    const int m = __builtin_amdgcn_update_dpp(0, __float_as_int(v), CTRL, 0xF, 0xF, true);
    return v + __int_as_float(m);
}
__device__ __forceinline__ float row16_sum(float v) {
    v = dpp_add<0xB1>(v);   // quad_perm xor1
    v = dpp_add<0x4E>(v);   // quad_perm xor2
    v = dpp_add<0x124>(v);  // row_ror:4
    v = dpp_add<0x128>(v);  // row_ror:8
    return v;
}

// pack hi16(ha):hi16(hb) -> one dword in ONE v_perm_b32
__device__ __forceinline__ unsigned pack_hi16(float ha, float hb) {
    return __builtin_amdgcn_perm(__float_as_uint(hb), __float_as_uint(ha), 0x07060302u);
}

// Pre-kernel: split W2 (64x64 fp32) into bf16 hi/lo planes in d_ws once.
__global__ __launch_bounds__(256) void w2split_kernel(
    const float* __restrict__ W2, short* __restrict__ w2h, short* __restrict__ w2l)
{
    const int i = blockIdx.x * 256 + threadIdx.x;
    if (i < 4096) {
        const float w = W2[i];
        const unsigned u = __float_as_uint(w);
        w2h[i] = (short)(u >> 16);
        const float l = w - __uint_as_float(u & 0xFFFF0000u);
        w2l[i] = (short)(__float_as_uint(l) >> 16);
    }
}

// R9 -> R10: B-fragments (were 64 resident VGPRs => 4 waves/SIMD, latency-
// bound at VALUBusy 43%) move to LDS (padded 72-short rows: 2-way bank
// aliasing only = free). Per-STEP ds_read_b128 with asm-opaqued offset to
// block LICM re-hoisting. Staging overlaps phase-1; barrier after phase-1.
__global__ __launch_bounds__(BLOCK_SIZE) void carnet_mfma(
    const float* __restrict__ x,      // (B, 9, 7) flat
    const int*   __restrict__ adj,    // (B, 45)
    const float* __restrict__ ctx,    // (B, 45)
    const float* __restrict__ gcn_W,  // (7, 7)
    const float* __restrict__ gcn_b,  // (7)
    const float* __restrict__ ctx_W,  // (45, 63)
    const float* __restrict__ ctx_b,  // (63)
    const float* __restrict__ W1,     // (64, 2)
    const float* __restrict__ b1,     // (64)
    const short* __restrict__ w2h,    // (64, 64) bf16 hi plane
    const short* __restrict__ w2l,    // (64, 64) bf16 lo plane
    const float* __restrict__ b2,     // (64)
    const float* __restrict__ W3,     // (2, 64)
    const float* __restrict__ b3,     // (2)
    float* __restrict__ out,          // (B, 2, 9, 7) flat
    int nbatch)
{
    __shared__ short sh2h[64 * 72];   // 9216 B, row stride 144 B (16B-aligned)
    __shared__ short sh2l[64 * 72];   // 9216 B

    const int t    = threadIdx.x;
    const int lane = t & 63;

    // ---- stage B planes global->LDS (overlaps phase-1; barrier later) ----
#pragma unroll
    for (int j0 = 0; j0 < 2; ++j0) {
        const int j = j0 * 256 + t;          // 0..511 uint4s per plane
        const int r = j >> 3, c = j & 7;
        *(uint4v*)&sh2h[r * 72 + c * 8] = ((const uint4v*)w2h)[j];
        *(uint4v*)&sh2l[r * 72 + c * 8] = ((const uint4v*)w2l)[j];
    }

    int bb_ = blockIdx.x * 4 + (t >> 6);
    bb_ = bb_ < nbatch ? bb_ : nbatch - 1;               // clamp, no divergence
    const int b = __builtin_amdgcn_readfirstlane(bb_);

    const int p = lane < 63 ? lane : 62;   // lane 63 duplicates position 62
    const int n = p / 7;
    const int f = p - n * 7;

    // ---- adjacency mask + degrees (wave-uniform: s_load + SALU) ----
    const int* ab = adj + b * 45;
    uint64_t am = 0;
#pragma unroll
    for (int i = 0; i < 45; ++i)
        am |= (uint64_t)(ab[i] != 0) << i;

    float d[9];
#pragma unroll
    for (int i = 0; i < 9; ++i) {
        const int s = 9 * i - (i * (i - 1)) / 2;
        const int w = 8 - i;
        const uint64_t bits = (am >> (s + 1)) & ((1ull << w) - 1ull);
        d[i] = __frsqrt_rn((float)(1 + __popcll(bits)));
    }

    // ---- y[m][f] once per (m,f) on lane m*7+f; gather for z ----
    const float* xb = x + b * 63;
    float yv = 0.f;
#pragma unroll
    for (int k = 0; k < 7; ++k)
        yv = fmaf(xb[n * 7 + k], gcn_W[k * 7 + f], yv);

    float zt = 0.f;
    const int snn = 9 * n - (n * (n - 1)) / 2 - n;   // sn - n
#pragma unroll
    for (int m = 0; m < 9; ++m) {
        const float ym = __shfl(yv, m * 7 + f);
        int sh = snn + m;
        sh = sh < 0 ? 0 : sh;
        const bool conn = (m == n) || ((m > n) && ((am >> sh) & 1ull));
        zt = fmaf(conn ? d[m] : 0.f, ym, zt);
    }
    const float zv = fmaf(d[n], zt, gcn_b[f]);

    // ---- c[p] = relu(ctx . ctx_W[:,p] + ctx_b[p]); ctx[q] is s_load ----
    const float* cb = ctx + b * 45;
    float cacc = ctx_b[p];
#pragma unroll
    for (int q = 0; q < 45; ++q)
        cacc = fmaf(cb[q], ctx_W[q * 63 + p], cacc);
    const float cvv = fmaxf(cacc, 0.f);

    // ================= PHASE 2: MFMA, 4 M-tiles per wave ================
    const int cl   = lane & 15;       // A row in tile / B column (och%16)
    const int quad = lane >> 4;       // k-octet selector / C row group
    const int boff = cl * 144 + quad * 16;   // byte offset into padded plane

    // Per-lane W1/b1 constants for this lane's 16 k-indices (resident).
    float2 wp0[8], wp1[8];
    float  bb0[8], bb1[8];
#pragma unroll
    for (int j = 0; j < 8; ++j) {
        const int o = quad * 8 + j;
        wp0[j] = *(const float2*)(W1 + 2 * o);
        bb0[j] = b1[o];
        wp1[j] = *(const float2*)(W1 + 2 * (o + 32));
        bb1[j] = b1[o + 32];
    }

    const float b2v0 = b2[cl],      b2v1 = b2[16 + cl];
    const float b2v2 = b2[32 + cl], b2v3 = b2[48 + cl];
    const float w3a0 = W3[cl],      w3a1 = W3[16 + cl];
    const float w3a2 = W3[32 + cl], w3a3 = W3[48 + cl];
    const float w3b0 = W3[64 + cl], w3b1 = W3[80 + cl];
    const float w3b2 = W3[96 + cl], w3b3 = W3[112 + cl];
    const float b30 = b3[0], b31 = b3[1];
    float* __restrict__ ob = out + b * 126;

    const char* sh2hB = (const char*)sh2h;
    const char* sh2lB = (const char*)sh2l;

    __syncthreads();   // staging complete before first B read

#pragma unroll 1
    for (int i = 0; i < 4; ++i) {
        const float zm = __shfl(zv,  i * 16 + cl);
        const float cm = __shfl(cvv, i * 16 + cl);

        // A fragments: h1[k] = relu(w0*z + w1*c + b); hi=trunc16, lo=residual.
        uint4v ph0, pl0, ph1, pl1;
#pragma unroll
        for (int jj = 0; jj < 4; ++jj) {
            float ha = fmaxf(fmaf(wp0[2*jj].x,   zm, fmaf(wp0[2*jj].y,   cm, bb0[2*jj])),   0.f);
            float hb = fmaxf(fmaf(wp0[2*jj+1].x, zm, fmaf(wp0[2*jj+1].y, cm, bb0[2*jj+1])), 0.f);
            ph0[jj] = pack_hi16(ha, hb);
            float la = ha - __uint_as_float(__float_as_uint(ha) & 0xFFFF0000u);
            float lb = hb - __uint_as_float(__float_as_uint(hb) & 0xFFFF0000u);
            pl0[jj] = pack_hi16(la, lb);

            ha = fmaxf(fmaf(wp1[2*jj].x,   zm, fmaf(wp1[2*jj].y,   cm, bb1[2*jj])),   0.f);
            hb = fmaxf(fmaf(wp1[2*jj+1].x, zm, fmaf(wp1[2*jj+1].y, cm, bb1[2*jj+1])), 0.f);
            ph1[jj] = pack_hi16(ha, hb);
            la = ha - __uint_as_float(__float_as_uint(ha) & 0xFFFF0000u);
            lb = hb - __uint_as_float(__float_as_uint(hb) & 0xFFFF0000u);
            pl1[jj] = pack_hi16(la, lb);
        }
        const bf16x8 ah0 = __builtin_bit_cast(bf16x8, ph0);
        const bf16x8 al0 = __builtin_bit_cast(bf16x8, pl0);
        const bf16x8 ah1 = __builtin_bit_cast(bf16x8, ph1);
        const bf16x8 al1 = __builtin_bit_cast(bf16x8, pl1);

        f32x4 acc0 = {b2v0, b2v0, b2v0, b2v0};
        f32x4 acc1 = {b2v1, b2v1, b2v1, b2v1};
        f32x4 acc2 = {b2v2, b2v2, b2v2, b2v2};
        f32x4 acc3 = {b2v3, b2v3, b2v3, b2v3};

        // B frags from LDS per STEP; asm-opaqued offset defeats LICM so they
        // are NOT hoisted back into 64 resident VGPRs (the R9 killer).
#define STEP(nt) {                                                                    \
        int bo = boff;                                                                \
        asm volatile("" : "+v"(bo));                                                  \
        const bf16x8 bh0 = *(const bf16x8*)(sh2hB + bo + ((nt) * 2304));              \
        const bf16x8 bh1 = *(const bf16x8*)(sh2hB + bo + ((nt) * 2304 + 64));         \
        const bf16x8 bl0 = *(const bf16x8*)(sh2lB + bo + ((nt) * 2304));              \
        const bf16x8 bl1 = *(const bf16x8*)(sh2lB + bo + ((nt) * 2304 + 64));         \
        acc##nt = __builtin_amdgcn_mfma_f32_16x16x32_bf16(ah0, bh0, acc##nt, 0, 0, 0); \
        acc##nt = __builtin_amdgcn_mfma_f32_16x16x32_bf16(al0, bh0, acc##nt, 0, 0, 0); \
        acc##nt = __builtin_amdgcn_mfma_f32_16x16x32_bf16(ah0, bl0, acc##nt, 0, 0, 0); \
        acc##nt = __builtin_amdgcn_mfma_f32_16x16x32_bf16(ah1, bh1, acc##nt, 0, 0, 0); \
        acc##nt = __builtin_amdgcn_mfma_f32_16x16x32_bf16(al1, bh1, acc##nt, 0, 0, 0); \
        acc##nt = __builtin_amdgcn_mfma_f32_16x16x32_bf16(ah1, bl1, acc##nt, 0, 0, 0); }
        STEP(0) STEP(1) STEP(2) STEP(3)
#undef STEP

        // Epilogue: h2 = relu(acc) (C layout: col=cl, row=quad*4+reg);
        // W3 dot per lane, DPP 16-lane reduction, lane cl==0 stores.
        const int ppBase = i * 16 + quad * 4;
#define REDST(reg) {                                                          \
        const float h20 = fmaxf(acc0[reg], 0.f);                              \
        const float h21 = fmaxf(acc1[reg], 0.f);                              \
        const float h22 = fmaxf(acc2[reg], 0.f);                              \
        const float h23 = fmaxf(acc3[reg], 0.f);                              \
        float q0 = fmaf(h23, w3a3, fmaf(h22, w3a2, fmaf(h21, w3a1, h20 * w3a0))); \
        float q1 = fmaf(h23, w3b3, fmaf(h22, w3b2, fmaf(h21, w3b1, h20 * w3b0))); \
        q0 = row16_sum(q0);                                                   \
        q1 = row16_sum(q1);                                                   \
        const int pp = ppBase + (reg);                                        \
        if (cl == 0 && pp < NPOS) {                                           \
            ob[pp]        = q0 + b30;                                         \
            ob[NPOS + pp] = q1 + b31;                                         \
        } }
        REDST(0) REDST(1) REDST(2) REDST(3)
#undef REDST
    }
}

extern "C" void kernel_launch(void* const* d_in, const int* in_sizes, int n_in,
                              void* d_out, int out_size, void* d_ws, size_t ws_size,
                              hipStream_t stream) {
    const float* x     = (const float*)d_in[0];
    const int*   adj   = (const int*)  d_in[1];
    const float* ctx   = (const float*)d_in[2];
    const float* gcn_W = (const float*)d_in[3];
    const float* gcn_b = (const float*)d_in[4];
    const float* ctx_W = (const float*)d_in[5];
    const float* ctx_b = (const float*)d_in[6];
    const float* W1    = (const float*)d_in[7];
    const float* b1    = (const float*)d_in[8];
    const float* W2    = (const float*)d_in[9];
    const float* b2    = (const float*)d_in[10];
    const float* W3    = (const float*)d_in[11];
    const float* b3    = (const float*)d_in[12];
    float* out = (float*)d_out;

    short* w2h = (short*)d_ws;          // 8 KB
    short* w2l = w2h + 4096;            // 8 KB

    w2split_kernel<<<16, 256, 0, stream>>>(W2, w2h, w2l);

    const int nbatch = in_sizes[1] / 45;            // B = 32768
    const int grid = (nbatch + 3) / 4;              // 4 batches (waves) per block
    carnet_mfma<<<grid, BLOCK_SIZE, 0, stream>>>(
        x, adj, ctx, gcn_W, gcn_b, ctx_W, ctx_b,
        W1, b1, w2h, w2l, b2, W3, b3, out, nbatch);
}

// Round 11
// 179.317 us; speedup vs baseline: 4.5084x; 1.0399x over previous
//
#include <hip/hip_runtime.h>
#include <cstdint>

#define BLOCK_SIZE 256
#define NPOS 63   // 9*7 spatial positions per batch

typedef __attribute__((ext_vector_type(8))) short bf16x8;       // 8 bf16, 4 VGPRs
typedef __attribute__((ext_vector_type(4))) float f32x4;
typedef __attribute__((ext_vector_type(4))) unsigned int uint4v;

// DPP 16-lane row reduction (VALU pipe, no LDS) — proven R8-R10.
template <int CTRL>
__device__ __forceinline__ float dpp_add(float v) {
    const int m = __builtin_amdgcn_update_dpp(0, __float_as_int(v), CTRL, 0xF, 0xF, true);
    return v + __int_as_float(m);
}
__device__ __forceinline__ float row16_sum(float v) {
    v = dpp_add<0xB1>(v);   // quad_perm xor1
    v = dpp_add<0x4E>(v);   // quad_perm xor2
    v = dpp_add<0x124>(v);  // row_ror:4
    v = dpp_add<0x128>(v);  // row_ror:8
    return v;
}

// pack hi16(ha):hi16(hb) -> one dword in ONE v_perm_b32
__device__ __forceinline__ unsigned pack_hi16(float ha, float hb) {
    return __builtin_amdgcn_perm(__float_as_uint(hb), __float_as_uint(ha), 0x07060302u);
}

// Pre-kernel: split W2 (64x64 fp32) into bf16 hi/lo planes in d_ws once.
__global__ __launch_bounds__(256) void w2split_kernel(
    const float* __restrict__ W2, short* __restrict__ w2h, short* __restrict__ w2l)
{
    const int i = blockIdx.x * 256 + threadIdx.x;
    if (i < 4096) {
        const float w = W2[i];
        const unsigned u = __float_as_uint(w);
        w2h[i] = (short)(u >> 16);
        const float l = w - __uint_as_float(u & 0xFFFF0000u);
        w2l[i] = (short)(__float_as_uint(l) >> 16);
    }
}

// KERNEL A: phase-1 (R10-proven, one wave = one batch, scalar adj/ctx/x).
// Stores float2{z,c} per position INTO d_out (bytes [b*504, b*504+504) ==
// exactly the range kernel B later overwrites for the same batch b — no
// cross-wave hazard; kernels are stream-ordered).
__global__ __launch_bounds__(BLOCK_SIZE) void carnet_zc(
    const float* __restrict__ x,      // (B, 9, 7) flat
    const int*   __restrict__ adj,    // (B, 45)
    const float* __restrict__ ctx,    // (B, 45)
    const float* __restrict__ gcn_W,  // (7, 7)
    const float* __restrict__ gcn_b,  // (7)
    const float* __restrict__ ctx_W,  // (45, 63)
    const float* __restrict__ ctx_b,  // (63)
    float2* __restrict__ zcbuf)       // (B*63) {z,c}  == d_out reinterpreted
{
    const int t    = threadIdx.x;
    const int lane = t & 63;
    const int b    = __builtin_amdgcn_readfirstlane(blockIdx.x * 4 + (t >> 6));

    const int p = lane < 63 ? lane : 62;
    const int n = p / 7;
    const int f = p - n * 7;

    // adjacency mask + degrees (wave-uniform: s_load + SALU)
    const int* ab = adj + b * 45;
    uint64_t am = 0;
#pragma unroll
    for (int i = 0; i < 45; ++i)
        am |= (uint64_t)(ab[i] != 0) << i;

    float d[9];
#pragma unroll
    for (int i = 0; i < 9; ++i) {
        const int s = 9 * i - (i * (i - 1)) / 2;
        const int w = 8 - i;
        const uint64_t bits = (am >> (s + 1)) & ((1ull << w) - 1ull);
        d[i] = __frsqrt_rn((float)(1 + __popcll(bits)));
    }

    // y[m][f] once per (m,f) on lane m*7+f; gather for z
    const float* xb = x + b * 63;
    float yv = 0.f;
#pragma unroll
    for (int k = 0; k < 7; ++k)
        yv = fmaf(xb[n * 7 + k], gcn_W[k * 7 + f], yv);

    float zt = 0.f;
    const int snn = 9 * n - (n * (n - 1)) / 2 - n;
#pragma unroll
    for (int m = 0; m < 9; ++m) {
        const float ym = __shfl(yv, m * 7 + f);
        int sh = snn + m;
        sh = sh < 0 ? 0 : sh;
        const bool conn = (m == n) || ((m > n) && ((am >> sh) & 1ull));
        zt = fmaf(conn ? d[m] : 0.f, ym, zt);
    }
    const float zv = fmaf(d[n], zt, gcn_b[f]);

    // c[p] = relu(ctx . ctx_W[:,p] + ctx_b[p]); ctx[q] s_load
    const float* cb = ctx + b * 45;
    float cacc = ctx_b[p];
#pragma unroll
    for (int q = 0; q < 45; ++q)
        cacc = fmaf(cb[q], ctx_W[q * 63 + p], cacc);
    const float cvv = fmaxf(cacc, 0.f);

    if (lane < 63)
        zcbuf[b * 63 + lane] = make_float2(zv, cvv);
}

// KERNEL B: pure GEMM machine. zc from global (coalesced float2), B-planes
// in XOR-swizzled UNPADDED LDS (chunk c of row r at slot c^(r&7)): staging
// writes AND fragment reads are exact min-2-way bank aliasing (free, m136)
// — fixes R10's 8.4M staging conflicts; LDS 18.4->16 KB.
__global__ __launch_bounds__(BLOCK_SIZE) void carnet_mfma(
    const float2* __restrict__ zcbuf, // (B*63) {z,c}  (aliases `out`)
    const float* __restrict__ W1,     // (64, 2)
    const float* __restrict__ b1,     // (64)
    const short* __restrict__ w2h,    // (64, 64) bf16 hi plane
    const short* __restrict__ w2l,    // (64, 64) bf16 lo plane
    const float* __restrict__ b2,     // (64)
    const float* __restrict__ W3,     // (2, 64)
    const float* __restrict__ b3,     // (2)
    float* __restrict__ out)          // (B, 2, 9, 7) flat
{
    __shared__ short sh2h[64 * 64];   // 8192 B, swizzled
    __shared__ short sh2l[64 * 64];   // 8192 B

    const int t    = threadIdx.x;
    const int lane = t & 63;
    const int b    = __builtin_amdgcn_readfirstlane(blockIdx.x * 4 + (t >> 6));

    // ---- stage B planes global->LDS, XOR-swizzled (2-way banks = free) ----
#pragma unroll
    for (int j0 = 0; j0 < 2; ++j0) {
        const int j = j0 * 256 + t;          // 16B chunk index, 0..511
        const int r = j >> 3, c = j & 7;
        const int slot = c ^ (r & 7);
        *(uint4v*)&sh2h[r * 64 + slot * 8] = ((const uint4v*)w2h)[j];
        *(uint4v*)&sh2l[r * 64 + slot * 8] = ((const uint4v*)w2l)[j];
    }

    // ---- zc for this wave's 63 (+1 dup) positions: one coalesced load ----
    const int pl = lane < 63 ? lane : 62;
    const float2 zc = zcbuf[b * 63 + pl];
    const float zv = zc.x, cvv = zc.y;

    const int cl   = lane & 15;       // A row in tile / B column (och%16)
    const int quad = lane >> 4;       // k-octet selector / C row group
    // swizzled byte offsets within a row: chunk quad and chunk quad+4
    const int s0 = (quad ^ (cl & 7)) * 16;      // ^64 gives second k-chunk

    // Per-lane W1/b1 constants for this lane's 16 k-indices (resident).
    float2 wp0[8], wp1[8];
    float  bb0[8], bb1[8];
#pragma unroll
    for (int j = 0; j < 8; ++j) {
        const int o = quad * 8 + j;
        wp0[j] = *(const float2*)(W1 + 2 * o);
        bb0[j] = b1[o];
        wp1[j] = *(const float2*)(W1 + 2 * (o + 32));
        bb1[j] = b1[o + 32];
    }

    const float b2v0 = b2[cl],      b2v1 = b2[16 + cl];
    const float b2v2 = b2[32 + cl], b2v3 = b2[48 + cl];
    const float w3a0 = W3[cl],      w3a1 = W3[16 + cl];
    const float w3a2 = W3[32 + cl], w3a3 = W3[48 + cl];
    const float w3b0 = W3[64 + cl], w3b1 = W3[80 + cl];
    const float w3b2 = W3[96 + cl], w3b3 = W3[112 + cl];
    const float b30 = b3[0], b31 = b3[1];
    float* __restrict__ ob = out + b * 126;

    const char* sh2hB = (const char*)sh2h;
    const char* sh2lB = (const char*)sh2l;

    __syncthreads();   // staging complete before first B read

#pragma unroll 1
    for (int i = 0; i < 4; ++i) {
        const float zm = __shfl(zv,  i * 16 + cl);
        const float cm = __shfl(cvv, i * 16 + cl);

        // A fragments: h1[k] = relu(w0*z + w1*c + b); hi=trunc16, lo=residual.
        uint4v ph0, pl0, ph1, pl1;
#pragma unroll
        for (int jj = 0; jj < 4; ++jj) {
            float ha = fmaxf(fmaf(wp0[2*jj].x,   zm, fmaf(wp0[2*jj].y,   cm, bb0[2*jj])),   0.f);
            float hb = fmaxf(fmaf(wp0[2*jj+1].x, zm, fmaf(wp0[2*jj+1].y, cm, bb0[2*jj+1])), 0.f);
            ph0[jj] = pack_hi16(ha, hb);
            float la = ha - __uint_as_float(__float_as_uint(ha) & 0xFFFF0000u);
            float lb = hb - __uint_as_float(__float_as_uint(hb) & 0xFFFF0000u);
            pl0[jj] = pack_hi16(la, lb);

            ha = fmaxf(fmaf(wp1[2*jj].x,   zm, fmaf(wp1[2*jj].y,   cm, bb1[2*jj])),   0.f);
            hb = fmaxf(fmaf(wp1[2*jj+1].x, zm, fmaf(wp1[2*jj+1].y, cm, bb1[2*jj+1])), 0.f);
            ph1[jj] = pack_hi16(ha, hb);
            la = ha - __uint_as_float(__float_as_uint(ha) & 0xFFFF0000u);
            lb = hb - __uint_as_float(__float_as_uint(hb) & 0xFFFF0000u);
            pl1[jj] = pack_hi16(la, lb);
        }
        const bf16x8 ah0 = __builtin_bit_cast(bf16x8, ph0);
        const bf16x8 al0 = __builtin_bit_cast(bf16x8, pl0);
        const bf16x8 ah1 = __builtin_bit_cast(bf16x8, ph1);
        const bf16x8 al1 = __builtin_bit_cast(bf16x8, pl1);

        f32x4 acc0 = {b2v0, b2v0, b2v0, b2v0};
        f32x4 acc1 = {b2v1, b2v1, b2v1, b2v1};
        f32x4 acc2 = {b2v2, b2v2, b2v2, b2v2};
        f32x4 acc3 = {b2v3, b2v3, b2v3, b2v3};

        // B frags from swizzled LDS per STEP; asm-opaqued offset defeats
        // LICM re-hoisting (the R9 killer). Row base = (nt*16+cl)*128 B,
        // k-chunks at swizzled s0 and s0^64.
#define STEP(nt) {                                                                    \
        int bo = cl * 128 + s0;                                                       \
        asm volatile("" : "+v"(bo));                                                  \
        const int bo2 = (cl * 128) | (s0 ^ 64);                                       \
        const bf16x8 bh0 = *(const bf16x8*)(sh2hB + bo  + ((nt) * 2048));             \
        const bf16x8 bh1 = *(const bf16x8*)(sh2hB + bo2 + ((nt) * 2048));             \
        const bf16x8 bl0 = *(const bf16x8*)(sh2lB + bo  + ((nt) * 2048));             \
        const bf16x8 bl1 = *(const bf16x8*)(sh2lB + bo2 + ((nt) * 2048));             \
        acc##nt = __builtin_amdgcn_mfma_f32_16x16x32_bf16(ah0, bh0, acc##nt, 0, 0, 0); \
        acc##nt = __builtin_amdgcn_mfma_f32_16x16x32_bf16(al0, bh0, acc##nt, 0, 0, 0); \
        acc##nt = __builtin_amdgcn_mfma_f32_16x16x32_bf16(ah0, bl0, acc##nt, 0, 0, 0); \
        acc##nt = __builtin_amdgcn_mfma_f32_16x16x32_bf16(ah1, bh1, acc##nt, 0, 0, 0); \
        acc##nt = __builtin_amdgcn_mfma_f32_16x16x32_bf16(al1, bh1, acc##nt, 0, 0, 0); \
        acc##nt = __builtin_amdgcn_mfma_f32_16x16x32_bf16(ah1, bl1, acc##nt, 0, 0, 0); }
        STEP(0) STEP(1) STEP(2) STEP(3)
#undef STEP

        // Epilogue: h2 = relu(acc) (C layout: col=cl, row=quad*4+reg);
        // W3 dot per lane, DPP 16-lane reduction, lane cl==0 stores.
        const int ppBase = i * 16 + quad * 4;
#define REDST(reg) {                                                          \
        const float h20 = fmaxf(acc0[reg], 0.f);                              \
        const float h21 = fmaxf(acc1[reg], 0.f);                              \
        const float h22 = fmaxf(acc2[reg], 0.f);                              \
        const float h23 = fmaxf(acc3[reg], 0.f);                              \
        float q0 = fmaf(h23, w3a3, fmaf(h22, w3a2, fmaf(h21, w3a1, h20 * w3a0))); \
        float q1 = fmaf(h23, w3b3, fmaf(h22, w3b2, fmaf(h21, w3b1, h20 * w3b0))); \
        q0 = row16_sum(q0);                                                   \
        q1 = row16_sum(q1);                                                   \
        const int pp = ppBase + (reg);                                        \
        if (cl == 0 && pp < NPOS) {                                           \
            ob[pp]        = q0 + b30;                                         \
            ob[NPOS + pp] = q1 + b31;                                         \
        } }
        REDST(0) REDST(1) REDST(2) REDST(3)
#undef REDST
    }
}

extern "C" void kernel_launch(void* const* d_in, const int* in_sizes, int n_in,
                              void* d_out, int out_size, void* d_ws, size_t ws_size,
                              hipStream_t stream) {
    const float* x     = (const float*)d_in[0];
    const int*   adj   = (const int*)  d_in[1];
    const float* ctx   = (const float*)d_in[2];
    const float* gcn_W = (const float*)d_in[3];
    const float* gcn_b = (const float*)d_in[4];
    const float* ctx_W = (const float*)d_in[5];
    const float* ctx_b = (const float*)d_in[6];
    const float* W1    = (const float*)d_in[7];
    const float* b1    = (const float*)d_in[8];
    const float* W2    = (const float*)d_in[9];
    const float* b2    = (const float*)d_in[10];
    const float* W3    = (const float*)d_in[11];
    const float* b3    = (const float*)d_in[12];
    float* out = (float*)d_out;

    short* w2h = (short*)d_ws;          // 8 KB
    short* w2l = w2h + 4096;            // 8 KB

    w2split_kernel<<<16, 256, 0, stream>>>(W2, w2h, w2l);

    const int nbatch = in_sizes[1] / 45;            // B = 32768
    const int grid = (nbatch + 3) / 4;              // 4 batches (waves) per block

    carnet_zc<<<grid, BLOCK_SIZE, 0, stream>>>(
        x, adj, ctx, gcn_W, gcn_b, ctx_W, ctx_b, (float2*)out);

    carnet_mfma<<<grid, BLOCK_SIZE, 0, stream>>>(
        (const float2*)out, W1, b1, w2h, w2l, b2, W3, b3, out);
}